// Round 1
// baseline (551.305 us; speedup 1.0000x reference)
//
#include <hip/hip_runtime.h>
#include <hip/hip_bf16.h>
#include <math.h>

#define NH 32
#define NKV 8
#define HD 64
#define B_ 2
#define S_ 2048
#define E_ 2048
#define M_ 4096   // B_*S_

typedef unsigned short ushort_t;
typedef __attribute__((ext_vector_type(8))) short short8;
typedef __attribute__((ext_vector_type(4))) short short4v;
typedef __attribute__((ext_vector_type(4))) float floatx4;

__device__ inline unsigned short f2bf(float f) {
  unsigned int u = __float_as_uint(f);
  return (unsigned short)((u + 0x7FFFu + ((u >> 16) & 1u)) >> 16);  // RNE
}

// async global->LDS, 16B per lane; lds base must be wave-uniform (HW adds lane*16)
__device__ inline void ld_lds16(const void* g, void* l) {
  __builtin_amdgcn_global_load_lds((__attribute__((address_space(1))) void*)g,
                                   (__attribute__((address_space(3))) void*)l, 16, 0, 0);
}

// ---------------- x fp32 -> bf16 ----------------
__global__ __launch_bounds__(256) void cast_x(const float* __restrict__ x,
                                              ushort_t* __restrict__ xb) {
  size_t i = ((size_t)blockIdx.x * 256 + threadIdx.x) * 8;
  float4 a = *(const float4*)(x + i);
  float4 b = *(const float4*)(x + i + 4);
  short8 o;
  o[0] = (short)f2bf(a.x); o[1] = (short)f2bf(a.y);
  o[2] = (short)f2bf(a.z); o[3] = (short)f2bf(a.w);
  o[4] = (short)f2bf(b.x); o[5] = (short)f2bf(b.y);
  o[6] = (short)f2bf(b.z); o[7] = (short)f2bf(b.w);
  *(short8*)(xb + i) = o;
}

// ---------------- transpose (R,C) fp32 -> (C,R) bf16 ----------------
__global__ __launch_bounds__(256) void transpose_w(const float* __restrict__ in,
                                                   ushort_t* __restrict__ out,
                                                   int R, int C) {
  __shared__ float tile[32][33];
  int c0 = blockIdx.x * 32, r0 = blockIdx.y * 32;
  int x = threadIdx.x, y0 = threadIdx.y;  // block (32,8)
  for (int i = 0; i < 4; i++) {
    int r = y0 + i * 8;
    tile[r][x] = in[(size_t)(r0 + r) * C + c0 + x];
  }
  __syncthreads();
  for (int i = 0; i < 4; i++) {
    int r = y0 + i * 8;
    out[(size_t)(c0 + r) * R + r0 + x] = f2bf(tile[x][r]);
  }
}

// ---------------- outv (B,NKV,S,HD) fp32 -> vt (B,NKV,HD,S) bf16 ----------------
__global__ __launch_bounds__(256) void transpose_v(const float* __restrict__ outv,
                                                   ushort_t* __restrict__ vt) {
  __shared__ float t64[64][65];
  int bg = blockIdx.y;        // 0..15
  int s0 = blockIdx.x * 64;   // 32 s-tiles
  int tid = threadIdx.x;
  size_t ibase = (size_t)bg * S_ * HD + (size_t)s0 * HD;
  for (int i = tid; i < 1024; i += 256) {
    int sr = i >> 4, dc = (i & 15) * 4;
    float4 v = *(const float4*)(outv + ibase + (size_t)sr * HD + dc);
    t64[sr][dc] = v.x; t64[sr][dc + 1] = v.y; t64[sr][dc + 2] = v.z; t64[sr][dc + 3] = v.w;
  }
  __syncthreads();
  size_t obase = (size_t)bg * HD * S_ + s0;
  for (int i = tid; i < 512; i += 256) {
    int d = i >> 3, ss = (i & 7) * 8;
    short8 o;
#pragma unroll
    for (int e = 0; e < 8; e++) o[e] = (short)f2bf(t64[ss + e][d]);
    *(short8*)(vt + obase + (size_t)d * S_ + ss) = o;
  }
}

// ---------------- fused QKV GEMM: xb(M,2048)bf16 @ WT^T, N=3072 ----------------
// 128x128 tile, BK=32, global_load_lds staging, unpadded LDS [128][32].
// n0<2048: Q+rope (pre-scaled by 0.125 for attention) -> qbf.
// 2048..2559: K+rope -> outk fp32 + kbf. else: V -> outv fp32.
__global__ __launch_bounds__(256) void gemm_qkv(const ushort_t* __restrict__ xb,
                                                const ushort_t* __restrict__ WT,
                                                ushort_t* __restrict__ qbf,
                                                float* __restrict__ outk,
                                                ushort_t* __restrict__ kbf,
                                                float* __restrict__ outv,
                                                const float* __restrict__ cosP,
                                                const float* __restrict__ sinP) {
  __shared__ __align__(16) ushort_t As[128][32];
  __shared__ __align__(16) ushort_t Bs[128][32];
  const int K = 2048;
  int tid = threadIdx.x;
  int m0 = blockIdx.y * 128, n0 = blockIdx.x * 128;
  int w = tid >> 6, lane = tid & 63;
  int wm = (w >> 1) * 64, wn = (w & 1) * 64;
  int lr = lane & 15, quad = lane >> 4;
  int srow = lane >> 2, soff = (lane & 3) * 16;  // staging: 16 rows x 64B per wave-issue
  floatx4 acc[4][4] = {};
  for (int kt = 0; kt < 64; kt++) {
    __syncthreads();
#pragma unroll
    for (int j = 0; j < 2; j++) {
      int r = j * 64 + w * 16;
      ld_lds16((const char*)(xb + (size_t)(m0 + r + srow) * K) + kt * 64 + soff,
               (char*)As + r * 64);
      ld_lds16((const char*)(WT + (size_t)(n0 + r + srow) * K) + kt * 64 + soff,
               (char*)Bs + r * 64);
    }
    __syncthreads();
    short8 af[4], bf[4];
#pragma unroll
    for (int i = 0; i < 4; i++) af[i] = *(const short8*)(&As[wm + i * 16 + lr][quad * 8]);
#pragma unroll
    for (int j = 0; j < 4; j++) bf[j] = *(const short8*)(&Bs[wn + j * 16 + lr][quad * 8]);
#pragma unroll
    for (int i = 0; i < 4; i++)
#pragma unroll
      for (int j = 0; j < 4; j++)
        acc[i][j] = __builtin_amdgcn_mfma_f32_16x16x32_bf16(af[i], bf[j], acc[i][j], 0, 0, 0);
  }
  // epilogues (C: row=quad*4+r, col=lr)
  if (n0 < 2048) {  // Q + rope -> qbf, pre-scaled by 1/sqrt(HD)=0.125 for attn
#pragma unroll
    for (int i = 0; i < 4; i++)
#pragma unroll
      for (int j = 0; j < 2; j++) {
        int d = j * 16 + lr;
#pragma unroll
        for (int r = 0; r < 4; r++) {
          int row = m0 + wm + i * 16 + quad * 4 + r;
          int s = row & (S_ - 1);
          float c = cosP[s * 64 + d], sn = sinP[s * 64 + d];
          float x1 = acc[i][j][r], x2 = acc[i][j + 2][r];
          size_t o = (size_t)row * 2048 + n0 + wn + d;
          qbf[o] = f2bf((x1 * c - x2 * sn) * 0.125f);
          qbf[o + 32] = f2bf((x2 * c + x1 * sn) * 0.125f);
        }
      }
  } else if (n0 < 2560) {  // K + rope -> outk fp32 + kbf bf16
    int h = (n0 - 2048 + wn) >> 6;
#pragma unroll
    for (int i = 0; i < 4; i++)
#pragma unroll
      for (int j = 0; j < 2; j++) {
        int d = j * 16 + lr;
#pragma unroll
        for (int r = 0; r < 4; r++) {
          int row = m0 + wm + i * 16 + quad * 4 + r;
          int s = row & (S_ - 1), b = row >> 11;
          float c = cosP[s * 64 + d], sn = sinP[s * 64 + d];
          float x1 = acc[i][j][r], x2 = acc[i][j + 2][r];
          float y1 = x1 * c - x2 * sn, y2 = x2 * c + x1 * sn;
          size_t o = ((size_t)(b * NKV + h) * S_ + s) * 64 + d;
          outk[o] = y1; outk[o + 32] = y2;
          kbf[o] = f2bf(y1); kbf[o + 32] = f2bf(y2);
        }
      }
  } else {  // V -> outv fp32
    int cv0 = n0 - 2560 + wn;
    int h = cv0 >> 6;
#pragma unroll
    for (int i = 0; i < 4; i++)
#pragma unroll
      for (int j = 0; j < 4; j++) {
        int d = j * 16 + lr;
#pragma unroll
        for (int r = 0; r < 4; r++) {
          int row = m0 + wm + i * 16 + quad * 4 + r;
          int s = row & (S_ - 1), b = row >> 11;
          outv[((size_t)(b * NKV + h) * S_ + s) * 64 + d] = acc[i][j][r];
        }
      }
  }
}

// ---------------- O GEMM: ctx(qbf) @ WoT^T -> y fp32 ----------------
__global__ __launch_bounds__(256) void gemm_o(const ushort_t* __restrict__ ctx,
                                              const ushort_t* __restrict__ WoT,
                                              float* __restrict__ y) {
  __shared__ __align__(16) ushort_t As[128][32];
  __shared__ __align__(16) ushort_t Bs[128][32];
  const int K = 2048, N = 2048;
  int tid = threadIdx.x;
  int m0 = blockIdx.y * 128, n0 = blockIdx.x * 128;
  int w = tid >> 6, lane = tid & 63;
  int wm = (w >> 1) * 64, wn = (w & 1) * 64;
  int lr = lane & 15, quad = lane >> 4;
  int srow = lane >> 2, soff = (lane & 3) * 16;
  floatx4 acc[4][4] = {};
  for (int kt = 0; kt < 64; kt++) {
    __syncthreads();
#pragma unroll
    for (int j = 0; j < 2; j++) {
      int r = j * 64 + w * 16;
      ld_lds16((const char*)(ctx + (size_t)(m0 + r + srow) * K) + kt * 64 + soff,
               (char*)As + r * 64);
      ld_lds16((const char*)(WoT + (size_t)(n0 + r + srow) * K) + kt * 64 + soff,
               (char*)Bs + r * 64);
    }
    __syncthreads();
    short8 af[4], bf[4];
#pragma unroll
    for (int i = 0; i < 4; i++) af[i] = *(const short8*)(&As[wm + i * 16 + lr][quad * 8]);
#pragma unroll
    for (int j = 0; j < 4; j++) bf[j] = *(const short8*)(&Bs[wn + j * 16 + lr][quad * 8]);
#pragma unroll
    for (int i = 0; i < 4; i++)
#pragma unroll
      for (int j = 0; j < 4; j++)
        acc[i][j] = __builtin_amdgcn_mfma_f32_16x16x32_bf16(af[i], bf[j], acc[i][j], 0, 0, 0);
  }
#pragma unroll
  for (int i = 0; i < 4; i++)
#pragma unroll
    for (int j = 0; j < 4; j++) {
      int row = m0 + wm + i * 16 + quad * 4;
      int col = n0 + wn + j * 16 + lr;
#pragma unroll
      for (int r = 0; r < 4; r++)
        y[(size_t)(row + r) * N + col] = acc[i][j][r];
    }
}

// ---------------- MFMA flash attention v3: barrier-free, direct-global K/V ----------------
// qbf: (B,S,NH,HD) bf16 roped+prescaled; kbf: (B,NKV,S,HD) bf16 roped; vt: (B,NKV,HD,S) bf16.
// grid (64 b*h, 32 qtiles reversed on y: longest dispatched first); block 256 = 4 waves x 16 qrows.
// K/V tiles are L1/L2-resident (256KB per (b,g)) -> fragment loads straight from global:
// no staging loop, no __syncthreads. Only P^T round-trips through per-wave LDS.
__global__ __launch_bounds__(256, 4) void attn2(ushort_t* __restrict__ q,
                                                const ushort_t* __restrict__ k,
                                                const ushort_t* __restrict__ vt) {
  __shared__ __align__(16) ushort_t Ps[4][16][72];  // per-wave P^T[qrow][key]
  int bh = blockIdx.x;
  int qt = 31 - blockIdx.y;  // longest first across the whole grid
  int b = bh >> 5, h = bh & 31, g = h >> 2;
  int tid = threadIdx.x;
  int w = tid >> 6, lane = tid & 63;
  int lr = lane & 15, quad = lane >> 4;

  int qg = qt * 64 + w * 16 + lr;  // this lane's query row
  short8 aq0, aq1;                 // Q B-frag (Q^T operand), pre-scaled by 0.125
  {
    const ushort_t* qp = q + ((size_t)(b * S_ + qg) * NH + h) * HD;
    aq0 = *(const short8*)(qp + quad * 8);
    aq1 = *(const short8*)(qp + 32 + quad * 8);
  }
  floatx4 od[4] = {};  // O^T[d=dn*16+quad*4+r][qrow=lr]
  float mi = -INFINITY, li = 0.f;
  // per-lane fragment base pointers
  const ushort_t* kp = k + (size_t)(b * NKV + g) * S_ * HD + (size_t)lr * HD + quad * 8;
  const ushort_t* vp = vt + (size_t)(b * NKV + g) * HD * S_ + (size_t)lr * S_ + quad * 8;

  for (int t = 0; t <= qt; t++) {
    // ---- K fragments direct from global (16 rows x 64B lines, fully coalesced) ----
    const ushort_t* kt = kp + (size_t)t * 64 * HD;
    short8 ka[8];
#pragma unroll
    for (int kn = 0; kn < 4; kn++) {
      ka[kn * 2] = *(const short8*)(kt + kn * 16 * HD);
      ka[kn * 2 + 1] = *(const short8*)(kt + kn * 16 * HD + 32);
    }
    // S^T = K · Q^T : 4 key-tiles (scores already scaled: Q carries 0.125)
    floatx4 sc[4];
#pragma unroll
    for (int kn = 0; kn < 4; kn++) {
      floatx4 c = {};
      c = __builtin_amdgcn_mfma_f32_16x16x32_bf16(ka[kn * 2], aq0, c, 0, 0, 0);
      c = __builtin_amdgcn_mfma_f32_16x16x32_bf16(ka[kn * 2 + 1], aq1, c, 0, 0, 0);
      sc[kn] = c;
    }
    // ---- issue V fragment loads now; latency hides under the softmax VALU work ----
    const ushort_t* vtt = vp + t * 64;
    short8 vf[8];
#pragma unroll
    for (int dn = 0; dn < 4; dn++) {
      vf[dn * 2] = *(const short8*)(vtt + (size_t)(dn * 16) * S_);
      vf[dn * 2 + 1] = *(const short8*)(vtt + (size_t)(dn * 16) * S_ + 32);
    }
    // ---- online softmax (per-lane 16 scores + cross-quad reduce) ----
    float pv[16];
#pragma unroll
    for (int kn = 0; kn < 4; kn++)
#pragma unroll
      for (int r = 0; r < 4; r++) pv[kn * 4 + r] = sc[kn][r];
    if (t == qt) {  // causal mask: diagonal tile only (wave-uniform branch)
#pragma unroll
      for (int e = 0; e < 16; e++) {
        int kg = t * 64 + (e >> 2) * 16 + quad * 4 + (e & 3);
        if (kg > qg) pv[e] = -INFINITY;
      }
    }
    float mx = pv[0];
#pragma unroll
    for (int e = 1; e < 16; e++) mx = fmaxf(mx, pv[e]);
    mx = fmaxf(mx, __shfl_xor(mx, 16));
    mx = fmaxf(mx, __shfl_xor(mx, 32));
    // defer-max (T13): only rescale when the running max grew by > 8
    if (__any(mx > mi + 8.f)) {
      float mn = fmaxf(mi, mx);
      float al = __expf(mi - mn);
      li *= al;
#pragma unroll
      for (int dn = 0; dn < 4; dn++) {
        od[dn][0] *= al; od[dn][1] *= al; od[dn][2] *= al; od[dn][3] *= al;
      }
      mi = mn;
    }
    float ps = 0.f;
#pragma unroll
    for (int e = 0; e < 16; e++) {
      pv[e] = __expf(pv[e] - mi);
      ps += pv[e];
    }
    ps += __shfl_xor(ps, 16);
    ps += __shfl_xor(ps, 32);
    li += ps;
    // ---- P -> bf16 via v_cvt_pk (RNE), store to per-wave LDS ----
#pragma unroll
    for (int kn = 0; kn < 4; kn++) {
      unsigned int u0, u1;
      asm("v_cvt_pk_bf16_f32 %0, %1, %2" : "=v"(u0) : "v"(pv[kn * 4 + 0]), "v"(pv[kn * 4 + 1]));
      asm("v_cvt_pk_bf16_f32 %0, %1, %2" : "=v"(u1) : "v"(pv[kn * 4 + 2]), "v"(pv[kn * 4 + 3]));
      uint2 uu; uu.x = u0; uu.y = u1;
      *(uint2*)(&Ps[w][lr][kn * 16 + quad * 4]) = uu;
    }
    // O^T += V^T · P^T (same-wave LDS round-trip; compiler inserts lgkm waits)
    short8 pb0 = *(const short8*)(&Ps[w][lr][quad * 8]);
    short8 pb1 = *(const short8*)(&Ps[w][lr][32 + quad * 8]);
#pragma unroll
    for (int dn = 0; dn < 4; dn++) {
      od[dn] = __builtin_amdgcn_mfma_f32_16x16x32_bf16(vf[dn * 2], pb0, od[dn], 0, 0, 0);
      od[dn] = __builtin_amdgcn_mfma_f32_16x16x32_bf16(vf[dn * 2 + 1], pb1, od[dn], 0, 0, 0);
    }
  }
  float inv = 1.f / li;
  ushort_t* outp = q + ((size_t)(b * S_ + qg) * NH + h) * HD;
#pragma unroll
  for (int dn = 0; dn < 4; dn++) {
    short4v u;
    u[0] = (short)f2bf(od[dn][0] * inv); u[1] = (short)f2bf(od[dn][1] * inv);
    u[2] = (short)f2bf(od[dn][2] * inv); u[3] = (short)f2bf(od[dn][3] * inv);
    *(short4v*)(outp + dn * 16 + quad * 4) = u;
  }
}

extern "C" void kernel_launch(void* const* d_in, const int* in_sizes, int n_in,
                              void* d_out, int out_size, void* d_ws, size_t ws_size,
                              hipStream_t stream) {
  const float* x = (const float*)d_in[0];
  const float* cosT = (const float*)d_in[2];
  const float* sinT = (const float*)d_in[3];
  const float* Wq = (const float*)d_in[4];
  const float* Wk = (const float*)d_in[5];
  const float* Wv = (const float*)d_in[6];
  const float* Wo = (const float*)d_in[7];

  char* ws = (char*)d_ws;
  ushort_t* WT = (ushort_t*)(ws);                 // 12 MB (3072, 2048): Wq^T | Wk^T | Wv^T
  ushort_t* WoT = (ushort_t*)(ws + 12582912);     //  8 MB (2048, 2048)
  ushort_t* xb = (ushort_t*)(ws + 20971520);      // 16 MB (M, 2048) bf16
  ushort_t* qbf = (ushort_t*)(ws + 37748736);     // 16 MB (B,S,NH,HD); ctx in-place
  ushort_t* kbf = (ushort_t*)(ws + 54525952);     //  4 MB (B,NKV,S,HD)
  ushort_t* vt = (ushort_t*)(ws + 58720256);      //  4 MB (B,NKV,HD,S) -> 60 MB total

  float* y = (float*)d_out;                            // (B,S,E) fp32
  float* outk = y + (size_t)M_ * E_;                   // (B,NKV,S,HD) fp32
  float* outv = outk + (size_t)B_ * NKV * S_ * HD;     // (B,NKV,S,HD) fp32

  cast_x<<<dim3(4096), 256, 0, stream>>>(x, xb);
  transpose_w<<<dim3(64, 64), dim3(32, 8), 0, stream>>>(Wq, WT, 2048, 2048);
  transpose_w<<<dim3(16, 64), dim3(32, 8), 0, stream>>>(Wk, WT + 2048 * 2048, 2048, 512);
  transpose_w<<<dim3(16, 64), dim3(32, 8), 0, stream>>>(Wv, WT + 2560 * 2048, 2048, 512);
  transpose_w<<<dim3(64, 64), dim3(32, 8), 0, stream>>>(Wo, WoT, 2048, 2048);

  gemm_qkv<<<dim3(24, 32), 256, 0, stream>>>(xb, WT, qbf, outk, kbf, outv, cosT, sinT);
  transpose_v<<<dim3(32, 16), 256, 0, stream>>>(outv, vt);

  attn2<<<dim3(64, 32), 256, 0, stream>>>(qbf, kbf, vt);

  gemm_o<<<dim3(16, 32), 256, 0, stream>>>(qbf, WoT, y);
}

// Round 2
// 360.624 us; speedup vs baseline: 1.5288x; 1.5288x over previous
//
#include <hip/hip_runtime.h>
#include <hip/hip_bf16.h>
#include <math.h>

#define NH 32
#define NKV 8
#define HD 64
#define B_ 2
#define S_ 2048
#define E_ 2048
#define M_ 4096   // B_*S_

typedef unsigned short ushort_t;
typedef __attribute__((ext_vector_type(8))) short short8;
typedef __attribute__((ext_vector_type(4))) short short4v;
typedef __attribute__((ext_vector_type(4))) float floatx4;

__device__ inline unsigned short f2bf(float f) {
  unsigned int u = __float_as_uint(f);
  return (unsigned short)((u + 0x7FFFu + ((u >> 16) & 1u)) >> 16);  // RNE
}

__device__ inline float fexp2(float x) {  // raw v_exp_f32 (HW is base-2)
  float r;
  asm("v_exp_f32 %0, %1" : "=v"(r) : "v"(x));
  return r;
}

// async global->LDS, 16B per lane; lds base must be wave-uniform (HW adds lane*16)
__device__ inline void ld_lds16(const void* g, void* l) {
  __builtin_amdgcn_global_load_lds((__attribute__((address_space(1))) void*)g,
                                   (__attribute__((address_space(3))) void*)l, 16, 0, 0);
}

// ---------------- x fp32 -> bf16 ----------------
__global__ __launch_bounds__(256) void cast_x(const float* __restrict__ x,
                                              ushort_t* __restrict__ xb) {
  size_t i = ((size_t)blockIdx.x * 256 + threadIdx.x) * 8;
  float4 a = *(const float4*)(x + i);
  float4 b = *(const float4*)(x + i + 4);
  short8 o;
  o[0] = (short)f2bf(a.x); o[1] = (short)f2bf(a.y);
  o[2] = (short)f2bf(a.z); o[3] = (short)f2bf(a.w);
  o[4] = (short)f2bf(b.x); o[5] = (short)f2bf(b.y);
  o[6] = (short)f2bf(b.z); o[7] = (short)f2bf(b.w);
  *(short8*)(xb + i) = o;
}

// ---------------- transpose (R,C) fp32 -> (C,R) bf16 ----------------
__global__ __launch_bounds__(256) void transpose_w(const float* __restrict__ in,
                                                   ushort_t* __restrict__ out,
                                                   int R, int C) {
  __shared__ float tile[32][33];
  int c0 = blockIdx.x * 32, r0 = blockIdx.y * 32;
  int x = threadIdx.x, y0 = threadIdx.y;  // block (32,8)
  for (int i = 0; i < 4; i++) {
    int r = y0 + i * 8;
    tile[r][x] = in[(size_t)(r0 + r) * C + c0 + x];
  }
  __syncthreads();
  for (int i = 0; i < 4; i++) {
    int r = y0 + i * 8;
    out[(size_t)(c0 + r) * R + r0 + x] = f2bf(tile[x][r]);
  }
}

// ---------------- outv (B,NKV,S,HD) fp32 -> vt TILED (bg, S/64, HD, 64) bf16, swizzled ----
// vt tile layout: 8KB contiguous per (bg, s-tile); within a tile, element (d, s_local)
// stored at d*64 + (s_local ^ ((d&7)*8))  [byte-level: ^((d&7)<<4)] for conflict-free b128.
__global__ __launch_bounds__(256) void transpose_v(const float* __restrict__ outv,
                                                   ushort_t* __restrict__ vt) {
  __shared__ float t64[64][65];
  int bg = blockIdx.y;        // 0..15
  int tt = blockIdx.x;        // s-tile 0..31
  int s0 = tt * 64;
  int tid = threadIdx.x;
  size_t ibase = (size_t)bg * S_ * HD + (size_t)s0 * HD;
  for (int i = tid; i < 1024; i += 256) {
    int sr = i >> 4, dc = (i & 15) * 4;
    float4 v = *(const float4*)(outv + ibase + (size_t)sr * HD + dc);
    t64[sr][dc] = v.x; t64[sr][dc + 1] = v.y; t64[sr][dc + 2] = v.z; t64[sr][dc + 3] = v.w;
  }
  __syncthreads();
  size_t obase = ((size_t)bg * 32 + tt) * 4096;  // 64*64 elements per tile
  for (int i = tid; i < 512; i += 256) {
    int d = i >> 3, ss = (i & 7) * 8;
    short8 o;
#pragma unroll
    for (int e = 0; e < 8; e++) o[e] = (short)f2bf(t64[ss + e][d]);
    *(short8*)(vt + obase + d * 64 + (ss ^ ((d & 7) << 3))) = o;
  }
}

// ---------------- fused QKV GEMM: xb(M,2048)bf16 @ WT^T, N=3072 ----------------
// 128x128 tile, BK=32, global_load_lds staging, unpadded LDS [128][32].
// n0<2048: Q+rope, pre-scaled by 0.125*log2e (attn works in exp2 domain) -> qbf.
// 2048..2559: K+rope -> outk fp32 (natural) + kbf bf16 (XOR-swizzled rows). else: V -> outv.
__global__ __launch_bounds__(256) void gemm_qkv(const ushort_t* __restrict__ xb,
                                                const ushort_t* __restrict__ WT,
                                                ushort_t* __restrict__ qbf,
                                                float* __restrict__ outk,
                                                ushort_t* __restrict__ kbf,
                                                float* __restrict__ outv,
                                                const float* __restrict__ cosP,
                                                const float* __restrict__ sinP) {
  __shared__ __align__(16) ushort_t As[128][32];
  __shared__ __align__(16) ushort_t Bs[128][32];
  const int K = 2048;
  int tid = threadIdx.x;
  int m0 = blockIdx.y * 128, n0 = blockIdx.x * 128;
  int w = tid >> 6, lane = tid & 63;
  int wm = (w >> 1) * 64, wn = (w & 1) * 64;
  int lr = lane & 15, quad = lane >> 4;
  int srow = lane >> 2, soff = (lane & 3) * 16;  // staging: 16 rows x 64B per wave-issue
  floatx4 acc[4][4] = {};
  for (int kt = 0; kt < 64; kt++) {
    __syncthreads();
#pragma unroll
    for (int j = 0; j < 2; j++) {
      int r = j * 64 + w * 16;
      ld_lds16((const char*)(xb + (size_t)(m0 + r + srow) * K) + kt * 64 + soff,
               (char*)As + r * 64);
      ld_lds16((const char*)(WT + (size_t)(n0 + r + srow) * K) + kt * 64 + soff,
               (char*)Bs + r * 64);
    }
    __syncthreads();
    short8 af[4], bf[4];
#pragma unroll
    for (int i = 0; i < 4; i++) af[i] = *(const short8*)(&As[wm + i * 16 + lr][quad * 8]);
#pragma unroll
    for (int j = 0; j < 4; j++) bf[j] = *(const short8*)(&Bs[wn + j * 16 + lr][quad * 8]);
#pragma unroll
    for (int i = 0; i < 4; i++)
#pragma unroll
      for (int j = 0; j < 4; j++)
        acc[i][j] = __builtin_amdgcn_mfma_f32_16x16x32_bf16(af[i], bf[j], acc[i][j], 0, 0, 0);
  }
  // epilogues (C: row=quad*4+r, col=lr)
  if (n0 < 2048) {  // Q + rope -> qbf, pre-scaled by 0.125*log2e
    const float QS = 0.125f * 1.4426950408889634f;
#pragma unroll
    for (int i = 0; i < 4; i++)
#pragma unroll
      for (int j = 0; j < 2; j++) {
        int d = j * 16 + lr;
#pragma unroll
        for (int r = 0; r < 4; r++) {
          int row = m0 + wm + i * 16 + quad * 4 + r;
          int s = row & (S_ - 1);
          float c = cosP[s * 64 + d], sn = sinP[s * 64 + d];
          float x1 = acc[i][j][r], x2 = acc[i][j + 2][r];
          size_t o = (size_t)row * 2048 + n0 + wn + d;
          qbf[o] = f2bf((x1 * c - x2 * sn) * QS);
          qbf[o + 32] = f2bf((x2 * c + x1 * sn) * QS);
        }
      }
  } else if (n0 < 2560) {  // K + rope -> outk fp32 (natural) + kbf bf16 (swizzled)
    int h = (n0 - 2048 + wn) >> 6;
#pragma unroll
    for (int i = 0; i < 4; i++)
#pragma unroll
      for (int j = 0; j < 2; j++) {
        int d = j * 16 + lr;
#pragma unroll
        for (int r = 0; r < 4; r++) {
          int row = m0 + wm + i * 16 + quad * 4 + r;
          int s = row & (S_ - 1), b = row >> 11;
          float c = cosP[s * 64 + d], sn = sinP[s * 64 + d];
          float x1 = acc[i][j][r], x2 = acc[i][j + 2][r];
          float y1 = x1 * c - x2 * sn, y2 = x2 * c + x1 * sn;
          size_t rowb = ((size_t)(b * NKV + h) * S_ + s) * 64;
          int xr = (s & 7) << 3;
          outk[rowb + d] = y1; outk[rowb + d + 32] = y2;
          kbf[rowb + (d ^ xr)] = f2bf(y1);
          kbf[rowb + ((d + 32) ^ xr)] = f2bf(y2);
        }
      }
  } else {  // V -> outv fp32
    int cv0 = n0 - 2560 + wn;
    int h = cv0 >> 6;
#pragma unroll
    for (int i = 0; i < 4; i++)
#pragma unroll
      for (int j = 0; j < 4; j++) {
        int d = j * 16 + lr;
#pragma unroll
        for (int r = 0; r < 4; r++) {
          int row = m0 + wm + i * 16 + quad * 4 + r;
          int s = row & (S_ - 1), b = row >> 11;
          outv[((size_t)(b * NKV + h) * S_ + s) * 64 + d] = acc[i][j][r];
        }
      }
  }
}

// ---------------- O GEMM: ctx(qbf) @ WoT^T -> y fp32 ----------------
__global__ __launch_bounds__(256) void gemm_o(const ushort_t* __restrict__ ctx,
                                              const ushort_t* __restrict__ WoT,
                                              float* __restrict__ y) {
  __shared__ __align__(16) ushort_t As[128][32];
  __shared__ __align__(16) ushort_t Bs[128][32];
  const int K = 2048, N = 2048;
  int tid = threadIdx.x;
  int m0 = blockIdx.y * 128, n0 = blockIdx.x * 128;
  int w = tid >> 6, lane = tid & 63;
  int wm = (w >> 1) * 64, wn = (w & 1) * 64;
  int lr = lane & 15, quad = lane >> 4;
  int srow = lane >> 2, soff = (lane & 3) * 16;
  floatx4 acc[4][4] = {};
  for (int kt = 0; kt < 64; kt++) {
    __syncthreads();
#pragma unroll
    for (int j = 0; j < 2; j++) {
      int r = j * 64 + w * 16;
      ld_lds16((const char*)(ctx + (size_t)(m0 + r + srow) * K) + kt * 64 + soff,
               (char*)As + r * 64);
      ld_lds16((const char*)(WoT + (size_t)(n0 + r + srow) * K) + kt * 64 + soff,
               (char*)Bs + r * 64);
    }
    __syncthreads();
    short8 af[4], bf[4];
#pragma unroll
    for (int i = 0; i < 4; i++) af[i] = *(const short8*)(&As[wm + i * 16 + lr][quad * 8]);
#pragma unroll
    for (int j = 0; j < 4; j++) bf[j] = *(const short8*)(&Bs[wn + j * 16 + lr][quad * 8]);
#pragma unroll
    for (int i = 0; i < 4; i++)
#pragma unroll
      for (int j = 0; j < 4; j++)
        acc[i][j] = __builtin_amdgcn_mfma_f32_16x16x32_bf16(af[i], bf[j], acc[i][j], 0, 0, 0);
  }
#pragma unroll
  for (int i = 0; i < 4; i++)
#pragma unroll
    for (int j = 0; j < 4; j++) {
      int row = m0 + wm + i * 16 + quad * 4;
      int col = n0 + wn + j * 16 + lr;
#pragma unroll
      for (int r = 0; r < 4; r++)
        y[(size_t)(row + r) * N + col] = acc[i][j][r];
    }
}

// ---------------- MFMA flash attention v4: 2-phase async DMA pipeline ----------------
// qbf: (B,S,NH,HD) bf16 roped, pre-scaled 0.125*log2e; kbf: (B,NKV,S,HD) bf16 row-swizzled;
// vt: tiled (bg, S/64, HD, 64) bf16 row-swizzled. block 256 = 4 waves x 16 qrows.
// Double-buffered K/V via global_load_lds (stage t+1 || compute t, 1 barrier/iter).
// All LDS tiles use byte ^= ((row&7)<<4) swizzle -> ds_read_b128 at bank minimum.
__global__ __launch_bounds__(256, 4) void attn2(ushort_t* __restrict__ q,
                                                const ushort_t* __restrict__ k,
                                                const ushort_t* __restrict__ vt) {
  __shared__ __align__(16) ushort_t KV[2][2][64][64];  // [buf][K/V][row][col], swizzled content
  __shared__ __align__(16) ushort_t Ps[4][16][64];     // per-wave P^T, swizzled
  int bh = blockIdx.x;
  int qt = 31 - blockIdx.y;  // longest first
  int b = bh >> 5, h = bh & 31, g = h >> 2;
  int tid = threadIdx.x;
  int w = tid >> 6, lane = tid & 63;
  int lr = lane & 15, quad = lane >> 4;

  int qg = qt * 64 + w * 16 + lr;  // this lane's query row
  short8 aq0, aq1;                 // Q B-frag (Q^T operand), pre-scaled
  {
    const ushort_t* qp = q + ((size_t)(b * S_ + qg) * NH + h) * HD;
    aq0 = *(const short8*)(qp + quad * 8);
    aq1 = *(const short8*)(qp + 32 + quad * 8);
  }
  floatx4 od[4] = {};  // O^T[d=dn*16+quad*4+r][qrow=lr]
  float mi = -INFINITY, li = 0.f;

  // staging pointers: each wave DMAs bytes [w*2048, w*2048+2048) of each 8KB tile
  const char* ksrc = (const char*)(k + (size_t)(b * NKV + g) * S_ * HD) + w * 2048 + lane * 16;
  const char* vsrc = (const char*)(vt + (size_t)(b * NKV + g) * S_ * HD) + w * 2048 + lane * 16;
  char* dB = (char*)&KV[0][0][0][0] + w * 2048;  // K region; +8192 = V region; +16384 = buf1

  // swizzled in-row read offsets (row ≡ lr mod 8 for all tile reads)
  int sw = (lr & 7) << 4;
  int ro0 = (quad * 16) ^ sw;
  int ro1 = (64 + quad * 16) ^ sw;
  char* Pw = (char*)&Ps[0][0][0] + w * 2048;

  // prologue: stage tile 0 -> buf 0
  ld_lds16(ksrc, dB);
  ld_lds16(ksrc + 1024, dB + 1024);
  ld_lds16(vsrc, dB + 8192);
  ld_lds16(vsrc + 1024, dB + 8192 + 1024);
  asm volatile("s_waitcnt vmcnt(0)" ::: "memory");
  __syncthreads();

  int cur = 0;
  for (int t = 0; t <= qt; t++) {
    // stage t+1 into buf^1 (async; completes under compute below)
    if (t < qt) {
      const char* kn = ksrc + (size_t)(t + 1) * 8192;
      const char* vn = vsrc + (size_t)(t + 1) * 8192;
      char* d = dB + (cur ^ 1) * 16384;
      ld_lds16(kn, d); ld_lds16(kn + 1024, d + 1024);
      ld_lds16(vn, d + 8192); ld_lds16(vn + 1024, d + 8192 + 1024);
    }
    const char* Kb = (const char*)&KV[cur][0][0][0];
    const char* Vb = (const char*)&KV[cur][1][0][0];
    // S^T = K · Q^T : 4 key-tiles (scores in log2 domain)
    floatx4 sc[4];
#pragma unroll
    for (int kn = 0; kn < 4; kn++) {
      short8 a0 = *(const short8*)(Kb + (kn * 16 + lr) * 128 + ro0);
      short8 a1 = *(const short8*)(Kb + (kn * 16 + lr) * 128 + ro1);
      floatx4 c = {};
      c = __builtin_amdgcn_mfma_f32_16x16x32_bf16(a0, aq0, c, 0, 0, 0);
      c = __builtin_amdgcn_mfma_f32_16x16x32_bf16(a1, aq1, c, 0, 0, 0);
      sc[kn] = c;
    }
    // online softmax (per-lane 16 scores + cross-quad reduce), exp2 domain
    float pv[16];
#pragma unroll
    for (int kn = 0; kn < 4; kn++)
#pragma unroll
      for (int r = 0; r < 4; r++) pv[kn * 4 + r] = sc[kn][r];
    if (t == qt) {  // causal mask: diagonal tile only (wave-uniform branch)
#pragma unroll
      for (int e = 0; e < 16; e++) {
        int kg = t * 64 + (e >> 2) * 16 + quad * 4 + (e & 3);
        if (kg > qg) pv[e] = -INFINITY;
      }
    }
    float mx = pv[0];
#pragma unroll
    for (int e = 1; e < 16; e++) mx = fmaxf(mx, pv[e]);
    mx = fmaxf(mx, __shfl_xor(mx, 16));
    mx = fmaxf(mx, __shfl_xor(mx, 32));
    if (__any(mx > mi + 11.5f)) {  // defer-max (T13), 11.5 log2-units ≈ 8 nats
      float mn = fmaxf(mi, mx);
      float al = fexp2(mi - mn);
      li *= al;
#pragma unroll
      for (int dn = 0; dn < 4; dn++) {
        od[dn][0] *= al; od[dn][1] *= al; od[dn][2] *= al; od[dn][3] *= al;
      }
      mi = mn;
    }
    float ps = 0.f;
#pragma unroll
    for (int e = 0; e < 16; e++) {
      pv[e] = fexp2(pv[e] - mi);
      ps += pv[e];
    }
    ps += __shfl_xor(ps, 16);
    ps += __shfl_xor(ps, 32);
    li += ps;
    // P -> bf16 via v_cvt_pk, store to per-wave swizzled LDS
#pragma unroll
    for (int kn = 0; kn < 4; kn++) {
      unsigned int u0, u1;
      asm("v_cvt_pk_bf16_f32 %0, %1, %2" : "=v"(u0) : "v"(pv[kn * 4 + 0]), "v"(pv[kn * 4 + 1]));
      asm("v_cvt_pk_bf16_f32 %0, %1, %2" : "=v"(u1) : "v"(pv[kn * 4 + 2]), "v"(pv[kn * 4 + 3]));
      uint2 uu; uu.x = u0; uu.y = u1;
      *(uint2*)(Pw + lr * 128 + ((kn * 32 + quad * 8) ^ sw)) = uu;
    }
    short8 pb0 = *(const short8*)(Pw + lr * 128 + ro0);
    short8 pb1 = *(const short8*)(Pw + lr * 128 + ro1);
    // O^T += V^T · P^T
#pragma unroll
    for (int dn = 0; dn < 4; dn++) {
      short8 va = *(const short8*)(Vb + (dn * 16 + lr) * 128 + ro0);
      short8 vb = *(const short8*)(Vb + (dn * 16 + lr) * 128 + ro1);
      od[dn] = __builtin_amdgcn_mfma_f32_16x16x32_bf16(va, pb0, od[dn], 0, 0, 0);
      od[dn] = __builtin_amdgcn_mfma_f32_16x16x32_bf16(vb, pb1, od[dn], 0, 0, 0);
    }
    // next tile's DMA must be done; all waves done reading buf before it's overwritten
    asm volatile("s_waitcnt vmcnt(0)" ::: "memory");
    __syncthreads();
    cur ^= 1;
  }
  float inv = 1.f / li;
  ushort_t* outp = q + ((size_t)(b * S_ + qg) * NH + h) * HD;
#pragma unroll
  for (int dn = 0; dn < 4; dn++) {
    short4v u;
    u[0] = (short)f2bf(od[dn][0] * inv); u[1] = (short)f2bf(od[dn][1] * inv);
    u[2] = (short)f2bf(od[dn][2] * inv); u[3] = (short)f2bf(od[dn][3] * inv);
    *(short4v*)(outp + dn * 16 + quad * 4) = u;
  }
}

extern "C" void kernel_launch(void* const* d_in, const int* in_sizes, int n_in,
                              void* d_out, int out_size, void* d_ws, size_t ws_size,
                              hipStream_t stream) {
  const float* x = (const float*)d_in[0];
  const float* cosT = (const float*)d_in[2];
  const float* sinT = (const float*)d_in[3];
  const float* Wq = (const float*)d_in[4];
  const float* Wk = (const float*)d_in[5];
  const float* Wv = (const float*)d_in[6];
  const float* Wo = (const float*)d_in[7];

  char* ws = (char*)d_ws;
  ushort_t* WT = (ushort_t*)(ws);                 // 12 MB (3072, 2048): Wq^T | Wk^T | Wv^T
  ushort_t* WoT = (ushort_t*)(ws + 12582912);     //  8 MB (2048, 2048)
  ushort_t* xb = (ushort_t*)(ws + 20971520);      // 16 MB (M, 2048) bf16
  ushort_t* qbf = (ushort_t*)(ws + 37748736);     // 16 MB (B,S,NH,HD); ctx in-place
  ushort_t* kbf = (ushort_t*)(ws + 54525952);     //  4 MB (B,NKV,S,HD) swizzled
  ushort_t* vt = (ushort_t*)(ws + 58720256);      //  4 MB tiled (bg,S/64,HD,64) swizzled

  float* y = (float*)d_out;                            // (B,S,E) fp32
  float* outk = y + (size_t)M_ * E_;                   // (B,NKV,S,HD) fp32
  float* outv = outk + (size_t)B_ * NKV * S_ * HD;     // (B,NKV,S,HD) fp32

  cast_x<<<dim3(4096), 256, 0, stream>>>(x, xb);
  transpose_w<<<dim3(64, 64), dim3(32, 8), 0, stream>>>(Wq, WT, 2048, 2048);
  transpose_w<<<dim3(16, 64), dim3(32, 8), 0, stream>>>(Wk, WT + 2048 * 2048, 2048, 512);
  transpose_w<<<dim3(16, 64), dim3(32, 8), 0, stream>>>(Wv, WT + 2560 * 2048, 2048, 512);
  transpose_w<<<dim3(64, 64), dim3(32, 8), 0, stream>>>(Wo, WoT, 2048, 2048);

  gemm_qkv<<<dim3(24, 32), 256, 0, stream>>>(xb, WT, qbf, outk, kbf, outv, cosT, sinT);
  transpose_v<<<dim3(32, 16), 256, 0, stream>>>(outv, vt);

  attn2<<<dim3(64, 32), 256, 0, stream>>>(qbf, kbf, vt);

  gemm_o<<<dim3(16, 32), 256, 0, stream>>>(qbf, WoT, y);
}

// Round 5
// 343.969 us; speedup vs baseline: 1.6028x; 1.0484x over previous
//
#include <hip/hip_runtime.h>
#include <hip/hip_bf16.h>
#include <math.h>

#define NH 32
#define NKV 8
#define HD 64
#define B_ 2
#define S_ 2048
#define E_ 2048
#define M_ 4096   // B_*S_

typedef unsigned short ushort_t;
typedef __attribute__((ext_vector_type(8))) short short8;
typedef __attribute__((ext_vector_type(4))) short short4v;
typedef __attribute__((ext_vector_type(4))) float floatx4;

__device__ inline unsigned short f2bf(float f) {
  unsigned int u = __float_as_uint(f);
  return (unsigned short)((u + 0x7FFFu + ((u >> 16) & 1u)) >> 16);  // RNE
}

__device__ inline float fexp2(float x) {  // raw v_exp_f32 (HW is base-2)
  float r;
  asm("v_exp_f32 %0, %1" : "=v"(r) : "v"(x));
  return r;
}

// async global->LDS, 16B per lane; lds base must be wave-uniform (HW adds lane*16)
__device__ inline void ld_lds16(const void* g, void* l) {
  __builtin_amdgcn_global_load_lds((__attribute__((address_space(1))) void*)g,
                                   (__attribute__((address_space(3))) void*)l, 16, 0, 0);
}

// ---------------- x fp32 -> bf16 ----------------
__global__ __launch_bounds__(256) void cast_x(const float* __restrict__ x,
                                              ushort_t* __restrict__ xb) {
  size_t i = ((size_t)blockIdx.x * 256 + threadIdx.x) * 8;
  float4 a = *(const float4*)(x + i);
  float4 b = *(const float4*)(x + i + 4);
  short8 o;
  o[0] = (short)f2bf(a.x); o[1] = (short)f2bf(a.y);
  o[2] = (short)f2bf(a.z); o[3] = (short)f2bf(a.w);
  o[4] = (short)f2bf(b.x); o[5] = (short)f2bf(b.y);
  o[6] = (short)f2bf(b.z); o[7] = (short)f2bf(b.w);
  *(short8*)(xb + i) = o;
}

// ---------------- transpose (R,C) fp32 -> (C,R) bf16 ----------------
__global__ __launch_bounds__(256) void transpose_w(const float* __restrict__ in,
                                                   ushort_t* __restrict__ out,
                                                   int R, int C) {
  __shared__ float tile[32][33];
  int c0 = blockIdx.x * 32, r0 = blockIdx.y * 32;
  int x = threadIdx.x, y0 = threadIdx.y;  // block (32,8)
  for (int i = 0; i < 4; i++) {
    int r = y0 + i * 8;
    tile[r][x] = in[(size_t)(r0 + r) * C + c0 + x];
  }
  __syncthreads();
  for (int i = 0; i < 4; i++) {
    int r = y0 + i * 8;
    out[(size_t)(c0 + r) * R + r0 + x] = f2bf(tile[x][r]);
  }
}

// ---------------- outv (B,NKV,S,HD) fp32 -> vt TILED (bg, S/64, HD, 64) bf16, swizzled ----
__global__ __launch_bounds__(256) void transpose_v(const float* __restrict__ outv,
                                                   ushort_t* __restrict__ vt) {
  __shared__ float t64[64][65];
  int bg = blockIdx.y;        // 0..15
  int tt = blockIdx.x;        // s-tile 0..31
  int s0 = tt * 64;
  int tid = threadIdx.x;
  size_t ibase = (size_t)bg * S_ * HD + (size_t)s0 * HD;
  for (int i = tid; i < 1024; i += 256) {
    int sr = i >> 4, dc = (i & 15) * 4;
    float4 v = *(const float4*)(outv + ibase + (size_t)sr * HD + dc);
    t64[sr][dc] = v.x; t64[sr][dc + 1] = v.y; t64[sr][dc + 2] = v.z; t64[sr][dc + 3] = v.w;
  }
  __syncthreads();
  size_t obase = ((size_t)bg * 32 + tt) * 4096;  // 64*64 elements per tile
  for (int i = tid; i < 512; i += 256) {
    int d = i >> 3, ss = (i & 7) * 8;
    short8 o;
#pragma unroll
    for (int e = 0; e < 8; e++) o[e] = (short)f2bf(t64[ss + e][d]);
    *(short8*)(vt + obase + d * 64 + (ss ^ ((d & 7) << 3))) = o;
  }
}

// ========== 128x128 / BK=64 GEMM core, T3 minimum 2-phase (single sync per K-tile) ==========
// 256 threads = 4 waves (2x2), per-wave C 64x64 = acc[4][4]. LDS 64 KiB: double-buffered
// A[128][64] + B[128][64] bf16, XOR-swizzled 16B chunks (LDS[row][c] = G[row][c^(row&7)]),
// staged via global_load_lds (linear dest, pre-swizzled per-lane source).
// BUFFER STRIDE = 16384 B (128 rows x 128 B) — round-4's 32768 stride wrote past the LDS
// allocation via the DMA path (the container-killer). All addresses now < 32768 per array.
// Per K-tile: stage(kt+1 -> buf^1) || {16 ds_read_b128 + 32 MFMA on buf} -> __syncthreads.
// __syncthreads (= vmcnt(0)+lgkmcnt(0)+barrier) IS the tile-end drain; DMA latency hides
// under the compute instead of being drained at issue.
__device__ __forceinline__ void gemm128_core(const ushort_t* __restrict__ Ag,   // + m0*2048
                                             const ushort_t* __restrict__ Bg,   // + n0*2048
                                             floatx4 (&acc)[4][4]) {
  __shared__ __align__(16) ushort_t As[2][128][64];
  __shared__ __align__(16) ushort_t Bs[2][128][64];
  int tid = threadIdx.x;
  int w = tid >> 6, lane = tid & 63;
  int wm = (w >> 1) * 64, wn = (w & 1) * 64;
  int lr = lane & 15, quad = lane >> 4;
  int sx = lr & 7;
  char* Asb = (char*)As;
  char* Bsb = (char*)Bs;

  // staging geometry: wave w covers LDS rows [w*32, w*32+32) in 4 slots of 8 rows.
  // lane -> (row_in_slot = lane>>3, chunk = lane&7); source chunk pre-swizzled by row&7
  // (row&7 == lane>>3 since w*32 and s*8 are multiples of 8).
  size_t so[4];
#pragma unroll
  for (int s = 0; s < 4; s++)
    so[s] = (size_t)(w * 32 + s * 8 + (lane >> 3)) * 4096 + (size_t)(((lane & 7) ^ (lane >> 3)) * 16);
  const char* abase = (const char*)Ag;
  const char* bbase = (const char*)Bg;

#define STAGE128(buf, kt)                                          \
  do {                                                             \
    size_t ko = (size_t)(kt) * 128;                                \
    char* Ad = Asb + (buf) * 16384 + w * 4096;                     \
    char* Bd = Bsb + (buf) * 16384 + w * 4096;                     \
    _Pragma("unroll") for (int s = 0; s < 4; s++) {                \
      ld_lds16(abase + so[s] + ko, Ad + s * 1024);                 \
      ld_lds16(bbase + so[s] + ko, Bd + s * 1024);                 \
    }                                                              \
  } while (0)

  // prologue: stage K-tile 0 into buf 0
  STAGE128(0, 0);
  __syncthreads();

  int cur = 0;
  for (int kt = 0; kt < 32; kt++) {
    if (kt < 31) STAGE128(cur ^ 1, kt + 1);  // issue BEFORE compute; lands by tile-end sync
    const char* Ab = Asb + cur * 16384;
    const char* Bb = Bsb + cur * 16384;
    short8 af[4][2], bfr[4][2];
#pragma unroll
    for (int i = 0; i < 4; i++) {
      size_t rb = (size_t)(wm + i * 16 + lr) * 128;
#pragma unroll
      for (int ks = 0; ks < 2; ks++)
        af[i][ks] = *(const short8*)(Ab + rb + (((ks * 4 + quad) ^ sx) << 4));
    }
#pragma unroll
    for (int j = 0; j < 4; j++) {
      size_t rb = (size_t)(wn + j * 16 + lr) * 128;
#pragma unroll
      for (int ks = 0; ks < 2; ks++)
        bfr[j][ks] = *(const short8*)(Bb + rb + (((ks * 4 + quad) ^ sx) << 4));
    }
#pragma unroll
    for (int i = 0; i < 4; i++)
#pragma unroll
      for (int j = 0; j < 4; j++) {
        acc[i][j] = __builtin_amdgcn_mfma_f32_16x16x32_bf16(af[i][0], bfr[j][0], acc[i][j], 0, 0, 0);
        acc[i][j] = __builtin_amdgcn_mfma_f32_16x16x32_bf16(af[i][1], bfr[j][1], acc[i][j], 0, 0, 0);
      }
    __syncthreads();  // vmcnt(0)+lgkmcnt(0)+barrier: kt+1 landed, all reads of cur done
    cur ^= 1;
  }
#undef STAGE128
}

// ---------------- fused QKV GEMM: xb(M,2048)bf16 @ WT^T, N=3072, 128^2 tiles ----------------
__global__ __launch_bounds__(256) void gemm_qkv(const ushort_t* __restrict__ xb,
                                                const ushort_t* __restrict__ WT,
                                                ushort_t* __restrict__ qbf,
                                                float* __restrict__ outk,
                                                ushort_t* __restrict__ kbf,
                                                float* __restrict__ outv,
                                                const float* __restrict__ cosP,
                                                const float* __restrict__ sinP) {
  // bijective XCD swizzle: nwg = 768 = 8*96
  int o = blockIdx.y * 24 + blockIdx.x;
  int swz = (o & 7) * 96 + (o >> 3);
  int n0 = (swz % 24) * 128, m0 = (swz / 24) * 128;
  int tid = threadIdx.x;
  int w = tid >> 6, lane = tid & 63;
  int wm = (w >> 1) * 64, wn = (w & 1) * 64;
  int lr = lane & 15, quad = lane >> 4;

  floatx4 acc[4][4] = {};
  gemm128_core(xb + (size_t)m0 * 2048, WT + (size_t)n0 * 2048, acc);

  // epilogues (C: row=quad*4+r, col=lr) — identical to verified round-2 mapping
  if (n0 < 2048) {  // Q + rope -> qbf, pre-scaled by 0.125*log2e
    const float QS = 0.125f * 1.4426950408889634f;
#pragma unroll
    for (int i = 0; i < 4; i++)
#pragma unroll
      for (int j = 0; j < 2; j++) {
        int d = j * 16 + lr;
#pragma unroll
        for (int r = 0; r < 4; r++) {
          int row = m0 + wm + i * 16 + quad * 4 + r;
          int s = row & (S_ - 1);
          float c = cosP[s * 64 + d], sn = sinP[s * 64 + d];
          float x1 = acc[i][j][r], x2 = acc[i][j + 2][r];
          size_t oo = (size_t)row * 2048 + n0 + wn + d;
          qbf[oo] = f2bf((x1 * c - x2 * sn) * QS);
          qbf[oo + 32] = f2bf((x2 * c + x1 * sn) * QS);
        }
      }
  } else if (n0 < 2560) {  // K + rope -> outk fp32 (natural) + kbf bf16 (row-swizzled)
    int h = (n0 - 2048 + wn) >> 6;
#pragma unroll
    for (int i = 0; i < 4; i++)
#pragma unroll
      for (int j = 0; j < 2; j++) {
        int d = j * 16 + lr;
#pragma unroll
        for (int r = 0; r < 4; r++) {
          int row = m0 + wm + i * 16 + quad * 4 + r;
          int s = row & (S_ - 1), b = row >> 11;
          float c = cosP[s * 64 + d], sn = sinP[s * 64 + d];
          float x1 = acc[i][j][r], x2 = acc[i][j + 2][r];
          float y1 = x1 * c - x2 * sn, y2 = x2 * c + x1 * sn;
          size_t rowb = ((size_t)(b * NKV + h) * S_ + s) * 64;
          int xr = (s & 7) << 3;
          outk[rowb + d] = y1; outk[rowb + d + 32] = y2;
          kbf[rowb + (d ^ xr)] = f2bf(y1);
          kbf[rowb + ((d + 32) ^ xr)] = f2bf(y2);
        }
      }
  } else {  // V -> outv fp32
    int h = (n0 - 2560 + wn) >> 6;
#pragma unroll
    for (int i = 0; i < 4; i++)
#pragma unroll
      for (int j = 0; j < 4; j++) {
        int d = j * 16 + lr;
#pragma unroll
        for (int r = 0; r < 4; r++) {
          int row = m0 + wm + i * 16 + quad * 4 + r;
          int s = row & (S_ - 1), b = row >> 11;
          outv[((size_t)(b * NKV + h) * S_ + s) * 64 + d] = acc[i][j][r];
        }
      }
  }
}

// ---------------- O GEMM: ctx(qbf) @ WoT^T -> y fp32, 128^2 tiles ----------------
__global__ __launch_bounds__(256) void gemm_o(const ushort_t* __restrict__ ctx,
                                              const ushort_t* __restrict__ WoT,
                                              float* __restrict__ y) {
  // bijective XCD swizzle: nwg = 512 = 8*64
  int o = blockIdx.y * 16 + blockIdx.x;
  int swz = (o & 7) * 64 + (o >> 3);
  int n0 = (swz % 16) * 128, m0 = (swz / 16) * 128;
  int tid = threadIdx.x;
  int w = tid >> 6, lane = tid & 63;
  int wm = (w >> 1) * 64, wn = (w & 1) * 64;
  int lr = lane & 15, quad = lane >> 4;

  floatx4 acc[4][4] = {};
  gemm128_core(ctx + (size_t)m0 * 2048, WoT + (size_t)n0 * 2048, acc);

#pragma unroll
  for (int i = 0; i < 4; i++)
#pragma unroll
    for (int j = 0; j < 4; j++) {
      int row = m0 + wm + i * 16 + quad * 4;
      int col = n0 + wn + j * 16 + lr;
#pragma unroll
      for (int r = 0; r < 4; r++)
        y[(size_t)(row + r) * 2048 + col] = acc[i][j][r];
    }
}

// ---------------- MFMA flash attention: 2-phase async DMA pipeline (unchanged, verified) ----
__global__ __launch_bounds__(256, 4) void attn2(ushort_t* __restrict__ q,
                                                const ushort_t* __restrict__ k,
                                                const ushort_t* __restrict__ vt) {
  __shared__ __align__(16) ushort_t KV[2][2][64][64];  // [buf][K/V][row][col], swizzled content
  __shared__ __align__(16) ushort_t Ps[4][16][64];     // per-wave P^T, swizzled
  int bh = blockIdx.x;
  int qt = 31 - blockIdx.y;  // longest first
  int b = bh >> 5, h = bh & 31, g = h >> 2;
  int tid = threadIdx.x;
  int w = tid >> 6, lane = tid & 63;
  int lr = lane & 15, quad = lane >> 4;

  int qg = qt * 64 + w * 16 + lr;  // this lane's query row
  short8 aq0, aq1;                 // Q B-frag (Q^T operand), pre-scaled
  {
    const ushort_t* qp = q + ((size_t)(b * S_ + qg) * NH + h) * HD;
    aq0 = *(const short8*)(qp + quad * 8);
    aq1 = *(const short8*)(qp + 32 + quad * 8);
  }
  floatx4 od[4] = {};  // O^T[d=dn*16+quad*4+r][qrow=lr]
  float mi = -INFINITY, li = 0.f;

  const char* ksrc = (const char*)(k + (size_t)(b * NKV + g) * S_ * HD) + w * 2048 + lane * 16;
  const char* vsrc = (const char*)(vt + (size_t)(b * NKV + g) * S_ * HD) + w * 2048 + lane * 16;
  char* dB = (char*)&KV[0][0][0][0] + w * 2048;  // K region; +8192 = V region; +16384 = buf1

  int sw = (lr & 7) << 4;
  int ro0 = (quad * 16) ^ sw;
  int ro1 = (64 + quad * 16) ^ sw;
  char* Pw = (char*)&Ps[0][0][0] + w * 2048;

  // prologue: stage tile 0 -> buf 0
  ld_lds16(ksrc, dB);
  ld_lds16(ksrc + 1024, dB + 1024);
  ld_lds16(vsrc, dB + 8192);
  ld_lds16(vsrc + 1024, dB + 8192 + 1024);
  asm volatile("s_waitcnt vmcnt(0)" ::: "memory");
  __syncthreads();

  int cur = 0;
  for (int t = 0; t <= qt; t++) {
    if (t < qt) {
      const char* kn = ksrc + (size_t)(t + 1) * 8192;
      const char* vn = vsrc + (size_t)(t + 1) * 8192;
      char* d = dB + (cur ^ 1) * 16384;
      ld_lds16(kn, d); ld_lds16(kn + 1024, d + 1024);
      ld_lds16(vn, d + 8192); ld_lds16(vn + 1024, d + 8192 + 1024);
    }
    const char* Kb = (const char*)&KV[cur][0][0][0];
    const char* Vb = (const char*)&KV[cur][1][0][0];
    floatx4 sc[4];
#pragma unroll
    for (int kn = 0; kn < 4; kn++) {
      short8 a0 = *(const short8*)(Kb + (kn * 16 + lr) * 128 + ro0);
      short8 a1 = *(const short8*)(Kb + (kn * 16 + lr) * 128 + ro1);
      floatx4 c = {};
      c = __builtin_amdgcn_mfma_f32_16x16x32_bf16(a0, aq0, c, 0, 0, 0);
      c = __builtin_amdgcn_mfma_f32_16x16x32_bf16(a1, aq1, c, 0, 0, 0);
      sc[kn] = c;
    }
    float pv[16];
#pragma unroll
    for (int kn = 0; kn < 4; kn++)
#pragma unroll
      for (int r = 0; r < 4; r++) pv[kn * 4 + r] = sc[kn][r];
    if (t == qt) {  // causal mask: diagonal tile only
#pragma unroll
      for (int e = 0; e < 16; e++) {
        int kg = t * 64 + (e >> 2) * 16 + quad * 4 + (e & 3);
        if (kg > qg) pv[e] = -INFINITY;
      }
    }
    float mx = pv[0];
#pragma unroll
    for (int e = 1; e < 16; e++) mx = fmaxf(mx, pv[e]);
    mx = fmaxf(mx, __shfl_xor(mx, 16));
    mx = fmaxf(mx, __shfl_xor(mx, 32));
    if (__any(mx > mi + 11.5f)) {  // defer-max (T13)
      float mn = fmaxf(mi, mx);
      float al = fexp2(mi - mn);
      li *= al;
#pragma unroll
      for (int dn = 0; dn < 4; dn++) {
        od[dn][0] *= al; od[dn][1] *= al; od[dn][2] *= al; od[dn][3] *= al;
      }
      mi = mn;
    }
    float ps = 0.f;
#pragma unroll
    for (int e = 0; e < 16; e++) {
      pv[e] = fexp2(pv[e] - mi);
      ps += pv[e];
    }
    ps += __shfl_xor(ps, 16);
    ps += __shfl_xor(ps, 32);
    li += ps;
#pragma unroll
    for (int kn = 0; kn < 4; kn++) {
      unsigned int u0, u1;
      asm("v_cvt_pk_bf16_f32 %0, %1, %2" : "=v"(u0) : "v"(pv[kn * 4 + 0]), "v"(pv[kn * 4 + 1]));
      asm("v_cvt_pk_bf16_f32 %0, %1, %2" : "=v"(u1) : "v"(pv[kn * 4 + 2]), "v"(pv[kn * 4 + 3]));
      uint2 uu; uu.x = u0; uu.y = u1;
      *(uint2*)(Pw + lr * 128 + ((kn * 32 + quad * 8) ^ sw)) = uu;
    }
    short8 pb0 = *(const short8*)(Pw + lr * 128 + ro0);
    short8 pb1 = *(const short8*)(Pw + lr * 128 + ro1);
#pragma unroll
    for (int dn = 0; dn < 4; dn++) {
      short8 va = *(const short8*)(Vb + (dn * 16 + lr) * 128 + ro0);
      short8 vb = *(const short8*)(Vb + (dn * 16 + lr) * 128 + ro1);
      od[dn] = __builtin_amdgcn_mfma_f32_16x16x32_bf16(va, pb0, od[dn], 0, 0, 0);
      od[dn] = __builtin_amdgcn_mfma_f32_16x16x32_bf16(vb, pb1, od[dn], 0, 0, 0);
    }
    asm volatile("s_waitcnt vmcnt(0)" ::: "memory");
    __syncthreads();
    cur ^= 1;
  }
  float inv = 1.f / li;
  ushort_t* outp = q + ((size_t)(b * S_ + qg) * NH + h) * HD;
#pragma unroll
  for (int dn = 0; dn < 4; dn++) {
    short4v u;
    u[0] = (short)f2bf(od[dn][0] * inv); u[1] = (short)f2bf(od[dn][1] * inv);
    u[2] = (short)f2bf(od[dn][2] * inv); u[3] = (short)f2bf(od[dn][3] * inv);
    *(short4v*)(outp + dn * 16 + quad * 4) = u;
  }
}

extern "C" void kernel_launch(void* const* d_in, const int* in_sizes, int n_in,
                              void* d_out, int out_size, void* d_ws, size_t ws_size,
                              hipStream_t stream) {
  const float* x = (const float*)d_in[0];
  const float* cosT = (const float*)d_in[2];
  const float* sinT = (const float*)d_in[3];
  const float* Wq = (const float*)d_in[4];
  const float* Wk = (const float*)d_in[5];
  const float* Wv = (const float*)d_in[6];
  const float* Wo = (const float*)d_in[7];

  char* ws = (char*)d_ws;
  ushort_t* WT = (ushort_t*)(ws);                 // 12 MB (3072, 2048): Wq^T | Wk^T | Wv^T
  ushort_t* WoT = (ushort_t*)(ws + 12582912);     //  8 MB (2048, 2048)
  ushort_t* xb = (ushort_t*)(ws + 20971520);      // 16 MB (M, 2048) bf16
  ushort_t* qbf = (ushort_t*)(ws + 37748736);     // 16 MB (B,S,NH,HD); ctx in-place
  ushort_t* kbf = (ushort_t*)(ws + 54525952);     //  4 MB (B,NKV,S,HD) swizzled
  ushort_t* vt = (ushort_t*)(ws + 58720256);      //  4 MB tiled (bg,S/64,HD,64) swizzled

  float* y = (float*)d_out;                            // (B,S,E) fp32
  float* outk = y + (size_t)M_ * E_;                   // (B,NKV,S,HD) fp32
  float* outv = outk + (size_t)B_ * NKV * S_ * HD;     // (B,NKV,S,HD) fp32

  cast_x<<<dim3(4096), 256, 0, stream>>>(x, xb);
  transpose_w<<<dim3(64, 64), dim3(32, 8), 0, stream>>>(Wq, WT, 2048, 2048);
  transpose_w<<<dim3(16, 64), dim3(32, 8), 0, stream>>>(Wk, WT + 2048 * 2048, 2048, 512);
  transpose_w<<<dim3(16, 64), dim3(32, 8), 0, stream>>>(Wv, WT + 2560 * 2048, 2048, 512);
  transpose_w<<<dim3(64, 64), dim3(32, 8), 0, stream>>>(Wo, WoT, 2048, 2048);

  gemm_qkv<<<dim3(24, 32), 256, 0, stream>>>(xb, WT, qbf, outk, kbf, outv, cosT, sinT);
  transpose_v<<<dim3(32, 16), 256, 0, stream>>>(outv, vt);

  attn2<<<dim3(64, 32), 256, 0, stream>>>(qbf, kbf, vt);

  gemm_o<<<dim3(16, 32), 256, 0, stream>>>(qbf, WoT, y);
}